// Round 6
// baseline (597.386 us; speedup 1.0000x reference)
//
#include <hip/hip_runtime.h>
#include <hip/hip_bf16.h>

typedef __attribute__((ext_vector_type(8))) short bf16x8;
typedef __attribute__((ext_vector_type(4))) float f32x4;

#define PCAP 768   // max points per p3 block (batch_len/split + slack)

// ---------------- Phase 0: pre-split conv_w into frag-ready hi/lo bf16 ----------------
__global__ void p0_wsplit(const float* __restrict__ convw,
                          short* __restrict__ whi, short* __restrict__ wlo)
{
    int e = blockIdx.x * 256 + threadIdx.x;
    if (e >= 2048) return;
    int lane = e & 63;
    int kstep = (e >> 6) & 7;
    int nt = e >> 9;
    int cluster = nt * 16 + (lane & 15);
    int ch0 = kstep * 32 + (lane >> 4) * 8;
    const float* src = convw + cluster * 256 + ch0;
    #pragma unroll
    for (int j = 0; j < 8; ++j) {
        float x = src[j];
        unsigned u = __float_as_uint(x);
        unsigned uh = u & 0xffff0000u;
        float r = x - __uint_as_float(uh);
        whi[e * 8 + j] = (short)(u >> 16);
        wlo[e * 8 + j] = (short)(__float_as_uint(r) >> 16);
    }
}

// ---------------- Phase 2a: per-batch counts (was p1's job) ----------------
__global__ __launch_bounds__(256) void p2a_count(
    const int* __restrict__ bids, int* __restrict__ cnts, int N)
{
    __shared__ int lcnt[8];
    const int t = threadIdx.x;
    if (t < 8) lcnt[t] = 0;
    __syncthreads();
    int p = blockIdx.x * 256 + t;
    if (p < N) atomicAdd(&lcnt[bids[p]], 1);
    __syncthreads();
    if (t < 8) atomicAdd(&cnts[t], lcnt[t]);
}

// ---------------- Phase 2: prefix + counting-sort scatter ----------------
__global__ void p2_offsets(const int* __restrict__ cnts, int* __restrict__ offs, int* __restrict__ cur)
{
    if (threadIdx.x == 0) {
        int acc = 0;
        for (int b = 0; b < 8; ++b) { offs[b] = acc; cur[b] = acc; acc += cnts[b]; }
        offs[8] = acc;
    }
}

__global__ __launch_bounds__(256) void p2_scatter(
    const int* __restrict__ bids, int* __restrict__ cur, int* __restrict__ perm, int N)
{
    __shared__ int lcnt[8], lbase[8];
    const int t = threadIdx.x;
    if (t < 8) lcnt[t] = 0;
    __syncthreads();
    int p = blockIdx.x * 256 + t;
    int b = 0, my = 0;
    bool ok = p < N;
    if (ok) { b = bids[p]; my = atomicAdd(&lcnt[b], 1); }
    __syncthreads();
    if (t < 8) lbase[t] = atomicAdd(&cur[t], lcnt[t]);
    __syncthreads();
    if (ok) perm[lbase[b] + my] = p;
}

// ---------------- Phase 3 (FUSED): norm + logits + softmax + aggregation ----------------
// Per 32-point chunk: FETCH gathers feat rows (lane=channel); ssq via 64-lane shuffle;
// xn staged split-bf16 into swizzled xsT; raw logits L0 = split(x)@split(W) via MFMA
// (A re-gathered per-lane from feat, L2-hot; W frags from global, L2-resident);
// cross-wave softmax of (L0*inv + bias) through padded LDS scratch writes soft
// straight into swizzled sT; aggregation MFMAs unchanged. 3 barriers/chunk.
// FETCH(q+1) issued after the logits loads -> prefetch overlaps softmax+agg.
__global__ __launch_bounds__(256, 2) void p3_fused(
    const float* __restrict__ feat, const short* __restrict__ whi,
    const short* __restrict__ wlo, const float* __restrict__ convb,
    const int* __restrict__ perm, const int* __restrict__ offs,
    float* __restrict__ partial, float* __restrict__ S, int split)
{
    __shared__ short xsT_hi[256 * 32];  // [c][p] 16 KB, slot-swizzled
    __shared__ short xsT_lo[256 * 32];  // 16 KB
    __shared__ short sT_hi[64 * 32];    // [k][p] 4 KB, slot-swizzled
    __shared__ short sT_lo[64 * 32];    // 4 KB
    __shared__ float logitsL[32 * 68];  // [p][k] padded to 68 -> bank spread (8.5 KB)
    __shared__ float invL32[32];
    __shared__ int   pidxL[PCAP];

    const int b  = blockIdx.x / split;
    const int sp = blockIdx.x % split;
    const int start = offs[b], end = offs[b + 1];
    const int len = end - start;
    const int chunk = (len + split - 1) / split;
    const int s0 = start + sp * chunk;
    int myLen = end - s0;
    myLen = max(0, min(myLen, chunk));
    myLen = min(myLen, PCAP);

    const int t = threadIdx.x;
    const int w = t >> 6, lane = t & 63;
    const int m = lane & 15, quad = lane >> 4;

    // pidxL fully initialized (tail = -1) so logits A-rows can read any chunk slot
    for (int i = t; i < PCAP; i += 256) pidxL[i] = (i < myLen) ? perm[s0 + i] : -1;
    __syncthreads();

    f32x4 acc[16];
    #pragma unroll
    for (int ct = 0; ct < 16; ++ct) acc[ct] = (f32x4){0.f, 0.f, 0.f, 0.f};
    float sacc[8];   // S partials: this thread covers k = (t&7) + 8u for its points
    #pragma unroll
    for (int u = 0; u < 8; ++u) sacc[u] = 0.f;
    float biask[8];
    #pragma unroll
    for (int u = 0; u < 8; ++u) biask[u] = convb[(t & 7) + 8 * u];

    const int nch = (myLen + 31) >> 5;
    const bf16x8* WH = (const bf16x8*)whi;
    const bf16x8* WL = (const bf16x8*)wlo;

    int   pids[8];
    float xv[4][8];
    auto FETCH = [&](int q) {
        #pragma unroll
        for (int j = 0; j < 8; ++j) pids[j] = pidxL[q * 32 + w * 8 + j];
        #pragma unroll
        for (int cg = 0; cg < 4; ++cg) {
            int c = cg * 64 + lane;
            #pragma unroll
            for (int j = 0; j < 8; ++j)
                xv[cg][j] = (pids[j] >= 0) ? feat[(size_t)pids[j] * 256 + c] : 0.f;
        }
    };
    if (nch > 0) FETCH(0);

    for (int q = 0; q < nch; ++q) {
        __syncthreads();   // [alpha] prev chunk's agg done reading xsT/sT
        // ---- ssq + inv (all lanes end up with every j's total)
        float inv[8];
        #pragma unroll
        for (int j = 0; j < 8; ++j) {
            float ss = xv[0][j]*xv[0][j] + xv[1][j]*xv[1][j]
                     + xv[2][j]*xv[2][j] + xv[3][j]*xv[3][j];
            #pragma unroll
            for (int off = 1; off < 64; off <<= 1) ss += __shfl_xor(ss, off);
            inv[j] = rsqrtf(fmaxf(ss, 1e-24f));
        }
        if (lane == 0) {
            #pragma unroll
            for (int j = 0; j < 8; ++j) invL32[w * 8 + j] = inv[j];
        }
        // ---- stage xn split-bf16 into xsT (swizzle slot = w ^ (c&3), as proven)
        #pragma unroll
        for (int cg = 0; cg < 4; ++cg) {
            int c = cg * 64 + lane;
            bf16x8 vh, vl;
            #pragma unroll
            for (int j = 0; j < 8; ++j) {
                float v = xv[cg][j] * inv[j];
                unsigned u = __float_as_uint(v);
                float r = v - __uint_as_float(u & 0xffff0000u);
                vh[j] = (short)(u >> 16);
                vl[j] = (short)(__float_as_uint(r) >> 16);
            }
            int slot = (w ^ (c & 3)) * 8;
            *(bf16x8*)&xsT_hi[c * 32 + slot] = vh;
            *(bf16x8*)&xsT_lo[c * 32 + slot] = vl;
        }
        // ---- logits: wave w owns p-tile (w>>1), k-tiles {2(w&1), 2(w&1)+1}
        const int ptile = w >> 1;
        const int kt0 = (w & 1) * 2;
        const int apid = pidxL[q * 32 + ptile * 16 + m];
        const float* abase = feat + (size_t)(apid >= 0 ? apid : 0) * 256 + quad * 8;
        f32x4 acc2[2];
        acc2[0] = (f32x4){0.f, 0.f, 0.f, 0.f};
        acc2[1] = (f32x4){0.f, 0.f, 0.f, 0.f};
        #pragma unroll
        for (int cs = 0; cs < 8; ++cs) {
            float4 a0 = *(const float4*)(abase + cs * 32);
            float4 a1 = *(const float4*)(abase + cs * 32 + 4);
            bf16x8 wh0 = WH[((kt0 + 0) * 8 + cs) * 64 + lane];
            bf16x8 wl0 = WL[((kt0 + 0) * 8 + cs) * 64 + lane];
            bf16x8 wh1 = WH[((kt0 + 1) * 8 + cs) * 64 + lane];
            bf16x8 wl1 = WL[((kt0 + 1) * 8 + cs) * 64 + lane];
            float xa[8] = {a0.x, a0.y, a0.z, a0.w, a1.x, a1.y, a1.z, a1.w};
            if (apid < 0) {
                #pragma unroll
                for (int j = 0; j < 8; ++j) xa[j] = 0.f;
            }
            bf16x8 ahi, alo;
            #pragma unroll
            for (int j = 0; j < 8; ++j) {
                unsigned u = __float_as_uint(xa[j]);
                float r = xa[j] - __uint_as_float(u & 0xffff0000u);
                ahi[j] = (short)(u >> 16);
                alo[j] = (short)(__float_as_uint(r) >> 16);
            }
            acc2[0] = __builtin_amdgcn_mfma_f32_16x16x32_bf16(ahi, wh0, acc2[0], 0, 0, 0);
            acc2[0] = __builtin_amdgcn_mfma_f32_16x16x32_bf16(ahi, wl0, acc2[0], 0, 0, 0);
            acc2[0] = __builtin_amdgcn_mfma_f32_16x16x32_bf16(alo, wh0, acc2[0], 0, 0, 0);
            acc2[1] = __builtin_amdgcn_mfma_f32_16x16x32_bf16(ahi, wh1, acc2[1], 0, 0, 0);
            acc2[1] = __builtin_amdgcn_mfma_f32_16x16x32_bf16(ahi, wl1, acc2[1], 0, 0, 0);
            acc2[1] = __builtin_amdgcn_mfma_f32_16x16x32_bf16(alo, wh1, acc2[1], 0, 0, 0);
        }
        // ---- issue next chunk's gathers NOW (newest in queue; fly under softmax+agg)
        if (q + 1 < nch) FETCH(q + 1);
        // ---- write raw logits (C/D: col=lane&15 -> k-in-tile, row=quad*4+r -> p-in-tile)
        #pragma unroll
        for (int kt = 0; kt < 2; ++kt)
            #pragma unroll
            for (int r = 0; r < 4; ++r)
                logitsL[(ptile * 16 + quad * 4 + r) * 68 + (kt0 + kt) * 16 + m] = acc2[kt][r];
        __syncthreads();   // [gamma] logits + invL32 visible
        // ---- softmax: 8 threads per point; thread (p=t>>3, s=t&7) handles k = s+8u
        {
            const int p = t >> 3, s = t & 7;
            const bool alive = (q * 32 + p) < myLen;
            float iv = invL32[p];
            float lg[8];
            #pragma unroll
            for (int u = 0; u < 8; ++u)
                lg[u] = logitsL[p * 68 + s + 8 * u] * iv + biask[u];
            float mx = lg[0];
            #pragma unroll
            for (int u = 1; u < 8; ++u) mx = fmaxf(mx, lg[u]);
            #pragma unroll
            for (int off = 1; off <= 4; off <<= 1) mx = fmaxf(mx, __shfl_xor(mx, off));
            float e[8];
            float ssum = 0.f;
            #pragma unroll
            for (int u = 0; u < 8; ++u) { e[u] = __expf(lg[u] - mx); ssum += e[u]; }
            #pragma unroll
            for (int off = 1; off <= 4; off <<= 1) ssum += __shfl_xor(ssum, off);
            float rs = 1.0f / ssum;
            #pragma unroll
            for (int u = 0; u < 8; ++u) {
                float sv = alive ? e[u] * rs : 0.f;
                sacc[u] += sv;
                int k = s + 8 * u;
                unsigned uu = __float_as_uint(sv);
                float rr = sv - __uint_as_float(uu & 0xffff0000u);
                int idx = k * 32 + (((p >> 3) ^ (k & 3)) * 8) + (p & 7);  // swizzled [k][p]
                sT_hi[idx] = (short)(uu >> 16);
                sT_lo[idx] = (short)(__float_as_uint(rr) >> 16);
            }
        }
        __syncthreads();   // [delta] sT ready
        // ---- aggregation: A = soft^T [k][p], B = xn^T [c][p] (proven r4 code)
        {
            const int arow = w * 16 + m;
            const int aslot = (quad ^ (m & 3)) * 8;
            bf16x8 ah = *(const bf16x8*)&sT_hi[arow * 32 + aslot];
            bf16x8 al = *(const bf16x8*)&sT_lo[arow * 32 + aslot];
            const int bslot = (quad ^ (m & 3)) * 8;
            #pragma unroll
            for (int ct = 0; ct < 16; ++ct) {
                const int brow = ct * 16 + m;
                bf16x8 bh = *(const bf16x8*)&xsT_hi[brow * 32 + bslot];
                bf16x8 bl = *(const bf16x8*)&xsT_lo[brow * 32 + bslot];
                acc[ct] = __builtin_amdgcn_mfma_f32_16x16x32_bf16(ah, bh, acc[ct], 0, 0, 0);
                acc[ct] = __builtin_amdgcn_mfma_f32_16x16x32_bf16(ah, bl, acc[ct], 0, 0, 0);
                acc[ct] = __builtin_amdgcn_mfma_f32_16x16x32_bf16(al, bh, acc[ct], 0, 0, 0);
            }
        }
    }

    // ---- S reduce: within wave over p-slots (lanes stride 8), then cross-wave via LDS
    #pragma unroll
    for (int u = 0; u < 8; ++u) {
        sacc[u] += __shfl_xor(sacc[u], 8);
        sacc[u] += __shfl_xor(sacc[u], 16);
        sacc[u] += __shfl_xor(sacc[u], 32);
    }
    __syncthreads();                 // all waves past their last agg; logitsL reusable
    float* swred = logitsL;          // [4][64]
    if (lane < 8) {
        #pragma unroll
        for (int u = 0; u < 8; ++u) swred[w * 64 + lane + 8 * u] = sacc[u];
    }
    __syncthreads();
    if (t < 64) {
        float sv = swred[t] + swred[64 + t] + swred[128 + t] + swred[192 + t];
        atomicAdd(S + b * 64 + t, sv);
    }

    // ---- write this block's partial 64x256 tile (no atomics)
    float* dst = partial + (size_t)(b * split + sp) * 64 * 256;
    #pragma unroll
    for (int ct = 0; ct < 16; ++ct) {
        #pragma unroll
        for (int r = 0; r < 4; ++r) {
            int k = w * 16 + quad * 4 + r;
            dst[k * 256 + ct * 16 + m] = acc[ct][r];
        }
    }
}

// ---------------- Phase 4a: reduce partials, subtract S*centroid, intra-normalize ----------------
__global__ __launch_bounds__(256) void p4a_vlad(
    const float* __restrict__ partial, const float* __restrict__ S,
    const float* __restrict__ cents, float* __restrict__ v, int split)
{
    const int b = blockIdx.x >> 6, k = blockIdx.x & 63;
    const int t = threadIdx.x;
    float sum = 0.f;
    const float* base = partial + ((size_t)(b * split) * 64 + k) * 256 + t;
    for (int sp = 0; sp < split; ++sp)
        sum += base[(size_t)sp * 64 * 256];
    float val = sum - S[b * 64 + k] * cents[k * 256 + t];
    float sq = val * val;
    #pragma unroll
    for (int off = 32; off >= 1; off >>= 1) sq += __shfl_xor(sq, off);
    __shared__ float wsum[4];
    if ((t & 63) == 0) wsum[t >> 6] = sq;
    __syncthreads();
    float tot = wsum[0] + wsum[1] + wsum[2] + wsum[3];
    float r = 1.0f / fmaxf(sqrtf(tot), 1e-12f);
    v[b * 16384 + k * 256 + t] = val * r;
}

// ---------------- Phase 4b: FC out = v @ fc_w.T + fc_b ----------------
__global__ __launch_bounds__(256) void p4b_fc(
    const float* __restrict__ v, const float* __restrict__ fcw,
    const float* __restrict__ fcb, float* __restrict__ pre)
{
    const int t = threadIdx.x;
    const int o0 = blockIdx.x * 4;
    float acc[4][8] = {};
    for (int it = 0; it < 64; ++it) {
        int i = it * 256 + t;
        float wv[4];
        #pragma unroll
        for (int oo = 0; oo < 4; ++oo) wv[oo] = fcw[(size_t)(o0 + oo) * 16384 + i];
        #pragma unroll
        for (int b = 0; b < 8; ++b) {
            float vv = v[b * 16384 + i];
            #pragma unroll
            for (int oo = 0; oo < 4; ++oo) acc[oo][b] += wv[oo] * vv;
        }
    }
    __shared__ float red[32][4];
    #pragma unroll
    for (int oo = 0; oo < 4; ++oo)
        #pragma unroll
        for (int b = 0; b < 8; ++b) {
            float sv = acc[oo][b];
            #pragma unroll
            for (int off = 32; off >= 1; off >>= 1) sv += __shfl_xor(sv, off);
            if ((t & 63) == 0) red[oo * 8 + b][t >> 6] = sv;
        }
    __syncthreads();
    if (t < 32) {
        int oo = t >> 3, b = t & 7;
        float sv = red[t][0] + red[t][1] + red[t][2] + red[t][3];
        pre[b * 1024 + o0 + oo] = sv + fcb[o0 + oo];
    }
}

// ---------------- Phase 5: final l2norm over 1024 ----------------
__global__ __launch_bounds__(256) void p5_norm(const float* __restrict__ pre, float* __restrict__ out)
{
    const int b = blockIdx.x, t = threadIdx.x;
    float vals[4];
    float sq = 0.f;
    #pragma unroll
    for (int i = 0; i < 4; ++i) {
        vals[i] = pre[b * 1024 + t + 256 * i];
        sq += vals[i] * vals[i];
    }
    #pragma unroll
    for (int off = 32; off >= 1; off >>= 1) sq += __shfl_xor(sq, off);
    __shared__ float wsum[4];
    if ((t & 63) == 0) wsum[t >> 6] = sq;
    __syncthreads();
    float tot = wsum[0] + wsum[1] + wsum[2] + wsum[3];
    float r = 1.0f / fmaxf(sqrtf(tot), 1e-12f);
    #pragma unroll
    for (int i = 0; i < 4; ++i) out[b * 1024 + t + 256 * i] = vals[i] * r;
}

extern "C" void kernel_launch(void* const* d_in, const int* in_sizes, int n_in,
                              void* d_out, int out_size, void* d_ws, size_t ws_size,
                              hipStream_t stream)
{
    const float* feat  = (const float*)d_in[0];
    const int*   bids  = (const int*)d_in[1];
    const float* cents = (const float*)d_in[2];
    const float* convw = (const float*)d_in[3];
    const float* convb = (const float*)d_in[4];
    const float* fcw   = (const float*)d_in[5];
    const float* fcb   = (const float*)d_in[6];
    float* out = (float*)d_out;

    const int N = in_sizes[0] / 256;  // 200000

    // ---- adaptive SPLIT (soft/invn buffers gone -> plenty of room; keep guard)
    const size_t base_floats = 16384 /*whi/wlo as shorts = 16384 floats*/
                             + 512 /*S*/ + 8 * 16384 /*v*/ + 8192 /*pre*/;
    const size_t base_ints = (size_t)N + 8 + 9 + 8;
    int split = 96;
    while (split > 16) {
        size_t tot = (base_floats + (size_t)split * 8 * 16384) * 4 + base_ints * 4;
        if (tot <= ws_size) break;
        split -= 16;
    }

    short* whi = (short*)d_ws;                    // 16384 shorts
    short* wlo = whi + 16384;                     // 16384 shorts
    float* partial = (float*)(wlo + 16384);       // split*8*64*256
    float* S    = partial + (size_t)split * 8 * 16384;  // 512
    float* v    = S + 512;                        // 8*16384
    float* pre  = v + 8 * 16384;                  // 8192
    int* perm = (int*)(pre + 8192);               // N
    int* cnts = perm + N;                         // 8
    int* offs = cnts + 8;                         // 9
    int* cur  = offs + 9;                         // 8

    hipMemsetAsync(S, 0, 512 * sizeof(float), stream);
    hipMemsetAsync(cnts, 0, 8 * sizeof(int), stream);

    p0_wsplit<<<8, 256, 0, stream>>>(convw, whi, wlo);
    p2a_count<<<(N + 255) / 256, 256, 0, stream>>>(bids, cnts, N);
    p2_offsets<<<1, 64, 0, stream>>>(cnts, offs, cur);
    p2_scatter<<<(N + 255) / 256, 256, 0, stream>>>(bids, cur, perm, N);
    p3_fused<<<8 * split, 256, 0, stream>>>(feat, whi, wlo, convb, perm, offs, partial, S, split);
    p4a_vlad<<<512, 256, 0, stream>>>(partial, S, cents, v, split);
    p4b_fc<<<256, 256, 0, stream>>>(v, fcw, fcb, pre);
    p5_norm<<<8, 256, 0, stream>>>(pre, out);
}